// Round 9
// baseline (131.227 us; speedup 1.0000x reference)
//
#include <hip/hip_runtime.h>
#include <hip/hip_bf16.h>
#include <math.h>

// Self_Attention_Local R9: repack-free attention.
//   Key change vs R8: the PV contraction's j-enumeration is redefined so the
//   score-MFMA C-layout (S^T tiles) IS the PV B-operand layout: per lane,
//   bp[jj] = exp(c[8g+jj]) with no cross-lane ops. The matching j-permutation
//   moves into the V A-fragment loads (2x ds_read_b64, hoisted once).
//   PV output O[p][i] (i on lanes) -> direct coalesced bf16 global stores:
//   ctx LDS staging + final barrier deleted.
//   k_conv (R8-verified): W permutes + emb->bf16. k_out: 512 blocks (2/CU).

typedef short bfrag  __attribute__((ext_vector_type(8)));   // 8 bf16 = 4 VGPRs
typedef float f32x4  __attribute__((ext_vector_type(4)));
typedef float f32x16 __attribute__((ext_vector_type(16)));

static __device__ __forceinline__ short f2bf(float x) {
    unsigned u = __builtin_bit_cast(unsigned, x);
    return (short)((u + 0x8000u) >> 16);       // round-half-up
}
static __device__ __forceinline__ float fast_exp2(float x) {
#if __has_builtin(__builtin_amdgcn_exp2f)
    return __builtin_amdgcn_exp2f(x);
#else
    return exp2f(x);
#endif
}
static __device__ __forceinline__ bfrag bzero() {
    bfrag z;
    #pragma unroll
    for (int j = 0; j < 8; ++j) z[j] = 0;
    return z;
}

// ---------------- k_conv: weights (R6-verified) + emb -> bf16 ----------------
__global__ __launch_bounds__(256) void k_conv(
    const float* __restrict__ Wq, const float* __restrict__ Wk,
    const float* __restrict__ Wv, const float* __restrict__ Wout,
    const float* __restrict__ emb,
    short* __restrict__ Wp, short* __restrict__ Wout_t, short* __restrict__ emb_bf)
{
    __shared__ short lt[4224];
    const int bid = blockIdx.x, t = threadIdx.x;
    if (bid < 96) {
        const int x = bid >> 5, h = (bid >> 2) & 7, k0 = (bid & 3) * 32;
        const float* W = (x == 0) ? Wq : (x == 1) ? Wk : Wv;
        #pragma unroll 4
        for (int rr = 0; rr < 16; ++rr) {
            const int k = rr * 2 + (t >> 7);
            const int i = t & 127;
            lt[k * 129 + i] = f2bf(W[(k0 + k) * 1024 + i * 8 + h]);
        }
        __syncthreads();
        short* dst = Wp + (x * 8 + h) * 16384;
        #pragma unroll
        for (int pp = 0; pp < 4; ++pp) {
            const int i  = pp * 32 + (t >> 3);
            const int kk = (t & 7) * 4;
            short4 v;
            v.x = lt[(kk + 0) * 129 + i]; v.y = lt[(kk + 1) * 129 + i];
            v.z = lt[(kk + 2) * 129 + i]; v.w = lt[(kk + 3) * 129 + i];
            *(short4*)&dst[i * 128 + k0 + kk] = v;
        }
    } else if (bid < 128) {
        const int b2 = bid - 96;
        const int cq = b2 >> 3, rq = b2 & 7;
        #pragma unroll 4
        for (int ii = 0; ii < 16; ++ii) {
            const int rr = ii * 8 + (t >> 5);
            const int cc = t & 31;
            lt[rr * 33 + cc] = f2bf(Wout[(rq * 128 + rr) * 128 + cq * 32 + cc]);
        }
        __syncthreads();
        #pragma unroll
        for (int ii = 0; ii < 4; ++ii) {
            const int task = ii * 256 + t;
            const int cl = task >> 5, hh = (task >> 2) & 7, mg = task & 3;
            short4 v;
            v.x = lt[(hh + 8 * (mg * 4 + 0)) * 33 + cl];
            v.y = lt[(hh + 8 * (mg * 4 + 1)) * 33 + cl];
            v.z = lt[(hh + 8 * (mg * 4 + 2)) * 33 + cl];
            v.w = lt[(hh + 8 * (mg * 4 + 3)) * 33 + cl];
            *(short4*)&Wout_t[(cq * 32 + cl) * 1024 + hh * 128 + rq * 16 + mg * 4] = v;
        }
    } else {
        const int base = (bid - 128) * 16384;
        #pragma unroll 4
        for (int u = 0; u < 16; ++u) {
            const int off = base + u * 1024 + t * 4;
            const float4 x = *(const float4*)&emb[off];
            short4 v;
            v.x = f2bf(x.x); v.y = f2bf(x.y); v.z = f2bf(x.z); v.w = f2bf(x.w);
            *(short4*)&emb_bf[off] = v;
        }
    }
}

// ---------------- k_attn ----------------
// LDS (shorts): QT 0..2047 Qt[pl][i][p] | KT 2048..4095 Kt[pl][j][p]
//               VS 4096..6143 Vs[pl][p][j] chunk-swizzled
#define QT 0
#define KT 2048
#define VS 4096

__global__ __launch_bounds__(256) void k_attn(
    const short* __restrict__ emb_bf,   // [4096][128] bf16
    const short* __restrict__ Wp,       // [3][8][128 i][128 k]
    short* __restrict__ ctx2)           // [4096 out-rows][h*128+i] bf16
{
    __shared__ short lds[6144];         // 12 KB
    __shared__ float redS[4], redQ[4];
    const int bid = blockIdx.x;         // 0..2047
    const int pp2 = bid >> 3, h = bid & 7;   // patch-pair, head
    const int t = threadIdx.x;
    const int w = t >> 6, lane = t & 63;
    const int m16 = lane & 15, quad = lane >> 4, q8 = quad * 8;
    const int l31 = lane & 31, hi = lane >> 5;
    const int pl = w >> 1, hf = w & 1;  // wave's patch (local) and band half

    // ===== QKV: (16x128) @ W_h (128x128) x3, 16x16x32 (R8-verified) =====
    {
        bfrag a[4];
        #pragma unroll
        for (int ks = 0; ks < 4; ++ks)
            a[ks] = *(const bfrag*)&emb_bf[(size_t)(pp2*16 + m16)*128 + ks*32 + q8];
        #pragma unroll
        for (int tt = 0; tt < 6; ++tt) {
            const int nt = w * 6 + tt;            // 0..23 = {q,k,v} x 8 i-tiles
            const int x  = nt >> 3;
            const int i0 = (nt & 7) * 16;
            const short* Wb = Wp + ((x*8 + h)*128 + i0 + m16) * 128;
            bfrag bb[4];
            #pragma unroll
            for (int ks = 0; ks < 4; ++ks)
                bb[ks] = *(const bfrag*)&Wb[ks*32 + q8];
            f32x4 c0 = {0.f,0.f,0.f,0.f};
            #pragma unroll
            for (int ks = 0; ks < 4; ++ks)
                c0 = __builtin_amdgcn_mfma_f32_16x16x32_bf16(a[ks], bb[ks], c0, 0,0,0);
            const int plt = quad >> 1;
            const int p0  = (quad & 1) * 4;
            const int col = i0 + m16;
            if (x < 2) {                          // Qt/Kt transposed [i][p]
                short4 v;
                v.x = f2bf(c0[0]); v.y = f2bf(c0[1]);
                v.z = f2bf(c0[2]); v.w = f2bf(c0[3]);
                *(short4*)&lds[(x ? KT : QT) + plt*1024 + col*8 + p0] = v;
            } else {                              // V natural, chunk-swizzled
                #pragma unroll
                for (int r = 0; r < 4; ++r) {
                    const int p = p0 + r;
                    const int phys = ((col >> 3) + p + 2*plt) & 15;
                    lds[VS + plt*1024 + p*128 + phys*8 + (col & 7)] = f2bf(c0[r]);
                }
            }
        }
    }
    __syncthreads();

    // ===== hoist fragments =====
    // V A-frags with the PERMUTED j-enumeration matching S^T C-layout:
    //   slot (kt=2mt+g, k=8hi+jj) <-> j = 32mt + 16g + 4hi + (jj&3) + 8(jj>>2)
    //   -> two short4 reads at logical j-offsets B0 and B0+8, B0 = 32mt+16g+4hi
    bfrag av[8];
    #pragma unroll
    for (int mt = 0; mt < 4; ++mt)
        #pragma unroll
        for (int g = 0; g < 2; ++g) {
            const int kt = 2*mt + g;
            if (l31 < 8) {
                const int base = VS + pl*1024 + l31*128;
                const int c0 = 4*mt + 2*g;
                const short4 lo = *(const short4*)
                    &lds[base + (((c0 + 0) + l31 + 2*pl) & 15)*8 + 4*hi];
                const short4 hi4 = *(const short4*)
                    &lds[base + (((c0 + 1) + l31 + 2*pl) & 15)*8 + 4*hi];
                bfrag f;
                f[0]=lo.x; f[1]=lo.y; f[2]=lo.z; f[3]=lo.w;
                f[4]=hi4.x; f[5]=hi4.y; f[6]=hi4.z; f[7]=hi4.w;
                av[kt] = f;
            } else if (l31 == 8) {      // ones row -> O row p=8 = rowsum_i
                bfrag o;
                #pragma unroll
                for (int j = 0; j < 8; ++j) o[j] = (short)0x3F80;
                av[kt] = o;
            } else
                av[kt] = bzero();
        }
    bfrag ak[4], bq[2];                 // scores: A[m=j][k=p], B[k=p][n=i]
    #pragma unroll
    for (int mt = 0; mt < 4; ++mt)
        ak[mt] = (hi == 0) ? *(const bfrag*)&lds[KT + pl*1024 + (32*mt + l31)*8] : bzero();
    #pragma unroll
    for (int u = 0; u < 2; ++u)
        bq[u] = (hi == 0) ? *(const bfrag*)&lds[QT + pl*1024 + (32*(2*hf+u) + l31)*8] : bzero();

    // ===== stats: this wave's 8 tiles, combine with partner via LDS =====
    float rs2, nbias;
    {
        float ls = 0.f, lq = 0.f;
        #pragma unroll
        for (int u = 0; u < 2; ++u)
            #pragma unroll
            for (int mt = 0; mt < 4; ++mt) {
                f32x16 c = {};
                c = __builtin_amdgcn_mfma_f32_32x32x16_bf16(ak[mt], bq[u], c, 0,0,0);
                #pragma unroll
                for (int r = 0; r < 16; ++r) { ls += c[r]; lq = fmaf(c[r], c[r], lq); }
            }
        #pragma unroll
        for (int off = 1; off <= 32; off <<= 1) {
            ls += __shfl_xor(ls, off);
            lq += __shfl_xor(lq, off);
        }
        if (lane == 0) { redS[w] = ls; redQ[w] = lq; }
        __syncthreads();
        const float st = redS[w] + redS[w ^ 1];
        const float qt = redQ[w] + redQ[w ^ 1];
        const float mean = st * (1.f / 16384.f);
        const float var  = qt * (1.f / 16384.f) - mean * mean;
        rs2   = rsqrtf(var + 1e-5f) * 1.44269504f;       // fold log2(e)
        nbias = -mean * rs2;
    }

    // out-row mapping (p = 4*hi + r for r = 0..3)
    int orow[4];
    {
        const int pat = pp2*2 + pl;
        const int bb = pat >> 5, rem = pat & 31;
        const int dd = rem >> 4, hh2 = (rem >> 2) & 3, ww2 = rem & 3;
        #pragma unroll
        for (int r = 0; r < 4; ++r) {
            const int p = 4*hi + r;
            const int p1 = p >> 2, p2 = (p >> 1) & 1, p3 = p & 1;
            orow[r] = bb*256 + ((((dd*2 + p1)*4 + hh2)*2 + p2)*4 + ww2)*2 + p3;
        }
    }

    // ===== pass 2: 2 bands: S^T -> exp (in-lane) -> PV -> direct store =====
    #pragma unroll
    for (int u = 0; u < 2; ++u) {
        const int ng = 2*hf + u;
        f32x16 O = {};
        #pragma unroll
        for (int mt = 0; mt < 4; ++mt) {
            f32x16 c = {};
            c = __builtin_amdgcn_mfma_f32_32x32x16_bf16(ak[mt], bq[u], c, 0,0,0);
            #pragma unroll
            for (int g = 0; g < 2; ++g) {
                bfrag bp;
                #pragma unroll
                for (int jj = 0; jj < 8; ++jj)
                    bp[jj] = f2bf(fast_exp2(fmaf(c[8*g + jj], rs2, nbias)));
                O = __builtin_amdgcn_mfma_f32_32x32x16_bf16(av[2*mt + g], bp, O, 0,0,0);
            }
        }
        // row sums live in O row p=8 = reg 4 on hi=0 lanes
        const float o4x  = __shfl_xor(O[4], 32);
        const float srow = hi ? o4x : O[4];
        const float iv   = __builtin_amdgcn_rcpf(srow);
        const int colg   = h*128 + 32*ng + l31;
        #pragma unroll
        for (int r = 0; r < 4; ++r)
            ctx2[(size_t)orow[r] * 1024 + colg] = f2bf(O[r] * iv);
    }
}

// ---------------- k_out: 512 blocks (2/CU), 8 rows each ----------------
__global__ __launch_bounds__(256) void k_out(
    const short* __restrict__ ctx2,    // [4096][1024]
    const short* __restrict__ Wout_t,  // [128 col][1024 k]
    float* __restrict__ out)           // [4096][128]
{
    const int t = threadIdx.x;
    const int w = t >> 6, lane = t & 63;
    const int m16 = lane & 15, quad = lane >> 4, q8 = quad * 8;
    const int row0 = blockIdx.x * 8;

    f32x4 acc0 = {0.f,0.f,0.f,0.f}, acc1 = {0.f,0.f,0.f,0.f};
    const short* ar = ctx2   + (size_t)(row0 + (m16 & 7)) * 1024 + q8;  // rows duplicated
    const short* b0 = Wout_t + (size_t)((w*2 + 0)*16 + m16) * 1024 + q8;
    const short* b1 = Wout_t + (size_t)((w*2 + 1)*16 + m16) * 1024 + q8;
    #pragma unroll 4
    for (int ks = 0; ks < 32; ++ks) {
        const bfrag a   = *(const bfrag*)&ar[ks*32];
        const bfrag vb0 = *(const bfrag*)&b0[ks*32];
        const bfrag vb1 = *(const bfrag*)&b1[ks*32];
        acc0 = __builtin_amdgcn_mfma_f32_16x16x32_bf16(a, vb0, acc0, 0, 0, 0);
        acc1 = __builtin_amdgcn_mfma_f32_16x16x32_bf16(a, vb1, acc1, 0, 0, 0);
    }
    if (quad < 2) {                    // C rows 0..7 valid (8..15 duplicates)
        #pragma unroll
        for (int r = 0; r < 4; ++r) {
            const int row = row0 + quad*4 + r;
            out[(size_t)row*128 + (w*2 + 0)*16 + m16] = acc0[r];
            out[(size_t)row*128 + (w*2 + 1)*16 + m16] = acc1[r];
        }
    }
}

extern "C" void kernel_launch(void* const* d_in, const int* in_sizes, int n_in,
                              void* d_out, int out_size, void* d_ws, size_t ws_size,
                              hipStream_t stream) {
    const float* emb  = (const float*)d_in[0];   // (512, 8, 128)
    const float* Wq   = (const float*)d_in[1];   // (128, 1024)
    const float* Wk   = (const float*)d_in[2];
    const float* Wv   = (const float*)d_in[3];
    const float* Wout = (const float*)d_in[4];   // (1024, 128)
    float* out = (float*)d_out;                  // 524288 floats

    short* ctx2   = (short*)d_ws;                // 4194304 shorts (8 MB)
    short* Wp     = ctx2 + 4194304;              // 393216
    short* Wout_t = Wp + 393216;                 // 131072
    short* emb_bf = Wout_t + 131072;             // 524288   (total ~10.1 MB)

    k_conv<<<160, 256, 0, stream>>>(Wq, Wk, Wv, Wout, emb, Wp, Wout_t, emb_bf);
    k_attn<<<2048, 256, 0, stream>>>(emb_bf, Wp, ctx2);
    k_out<<<512, 256, 0, stream>>>(ctx2, Wout_t, out);
}

// Round 10
// 124.086 us; speedup vs baseline: 1.0575x; 1.0575x over previous
//
#include <hip/hip_runtime.h>
#include <hip/hip_bf16.h>
#include <math.h>

// Self_Attention_Local R10: 4-waves-per-map attention (512-thread blocks).
//   vs R9: each (patch,head) map now served by 4 waves (1 pass-2 band each,
//   4 stats tiles each, 3 QKV tiles each) -> per-wave serial chain halves.
//   Packed bf16 conversion via v_perm (2 elts/op). Sides reverted to the
//   R7-proven shapes: k_conv 160 blocks (W permutes + emb cvt), k_out 256
//   blocks full-M. Repack-free PV (R9-verified j-enumeration), folded
//   softmax (no row max: scores are instance-normalized), ones-row rowsums.

typedef short bfrag  __attribute__((ext_vector_type(8)));   // 8 bf16 = 4 VGPRs
typedef float f32x4  __attribute__((ext_vector_type(4)));
typedef float f32x16 __attribute__((ext_vector_type(16)));
typedef int   i32x4  __attribute__((ext_vector_type(4)));

static __device__ __forceinline__ short f2bf(float x) {
    unsigned u = __builtin_bit_cast(unsigned, x);
    return (short)((u + 0x8000u) >> 16);       // round-half-up
}
// pack bf16(fhi):bf16(flo) into one int (flo in low short)
static __device__ __forceinline__ int f2bf_pk(float fhi, float flo) {
    unsigned uh = __builtin_bit_cast(unsigned, fhi) + 0x8000u;
    unsigned ul = __builtin_bit_cast(unsigned, flo) + 0x8000u;
#if __has_builtin(__builtin_amdgcn_perm)
    return (int)__builtin_amdgcn_perm(uh, ul, 0x07060302u);  // bytes lo.2,lo.3,hi.2,hi.3
#else
    return (int)((ul >> 16) | (uh & 0xffff0000u));
#endif
}
static __device__ __forceinline__ float fast_exp2(float x) {
#if __has_builtin(__builtin_amdgcn_exp2f)
    return __builtin_amdgcn_exp2f(x);
#else
    return exp2f(x);
#endif
}
static __device__ __forceinline__ bfrag bzero() {
    bfrag z;
    #pragma unroll
    for (int j = 0; j < 8; ++j) z[j] = 0;
    return z;
}

// ---------------- k_conv: weights (R6-verified) + emb -> bf16 ----------------
__global__ __launch_bounds__(256) void k_conv(
    const float* __restrict__ Wq, const float* __restrict__ Wk,
    const float* __restrict__ Wv, const float* __restrict__ Wout,
    const float* __restrict__ emb,
    short* __restrict__ Wp, short* __restrict__ Wout_t, short* __restrict__ emb_bf)
{
    __shared__ short lt[4224];
    const int bid = blockIdx.x, t = threadIdx.x;
    if (bid < 96) {
        const int x = bid >> 5, h = (bid >> 2) & 7, k0 = (bid & 3) * 32;
        const float* W = (x == 0) ? Wq : (x == 1) ? Wk : Wv;
        #pragma unroll 4
        for (int rr = 0; rr < 16; ++rr) {
            const int k = rr * 2 + (t >> 7);
            const int i = t & 127;
            lt[k * 129 + i] = f2bf(W[(k0 + k) * 1024 + i * 8 + h]);
        }
        __syncthreads();
        short* dst = Wp + (x * 8 + h) * 16384;
        #pragma unroll
        for (int pp = 0; pp < 4; ++pp) {
            const int i  = pp * 32 + (t >> 3);
            const int kk = (t & 7) * 4;
            short4 v;
            v.x = lt[(kk + 0) * 129 + i]; v.y = lt[(kk + 1) * 129 + i];
            v.z = lt[(kk + 2) * 129 + i]; v.w = lt[(kk + 3) * 129 + i];
            *(short4*)&dst[i * 128 + k0 + kk] = v;
        }
    } else if (bid < 128) {
        const int b2 = bid - 96;
        const int cq = b2 >> 3, rq = b2 & 7;
        #pragma unroll 4
        for (int ii = 0; ii < 16; ++ii) {
            const int rr = ii * 8 + (t >> 5);
            const int cc = t & 31;
            lt[rr * 33 + cc] = f2bf(Wout[(rq * 128 + rr) * 128 + cq * 32 + cc]);
        }
        __syncthreads();
        #pragma unroll
        for (int ii = 0; ii < 4; ++ii) {
            const int task = ii * 256 + t;
            const int cl = task >> 5, hh = (task >> 2) & 7, mg = task & 3;
            short4 v;
            v.x = lt[(hh + 8 * (mg * 4 + 0)) * 33 + cl];
            v.y = lt[(hh + 8 * (mg * 4 + 1)) * 33 + cl];
            v.z = lt[(hh + 8 * (mg * 4 + 2)) * 33 + cl];
            v.w = lt[(hh + 8 * (mg * 4 + 3)) * 33 + cl];
            *(short4*)&Wout_t[(cq * 32 + cl) * 1024 + hh * 128 + rq * 16 + mg * 4] = v;
        }
    } else {
        const int base = (bid - 128) * 16384;
        #pragma unroll 4
        for (int u = 0; u < 16; ++u) {
            const int off = base + u * 1024 + t * 4;
            const float4 x = *(const float4*)&emb[off];
            int2 v;
            v.x = f2bf_pk(x.y, x.x);
            v.y = f2bf_pk(x.w, x.z);
            *(int2*)&emb_bf[off] = v;
        }
    }
}

// ---------------- k_attn: 512 threads, 8 waves = 2 maps x 4 waves ------------
// LDS (shorts): QT 0..2047 Qt[pl][i][p] | KT 2048..4095 Kt[pl][j][p]
//               VS 4096..6143 Vs[pl][p][j] chunk-swizzled
#define QT 0
#define KT 2048
#define VS 4096

__global__ __launch_bounds__(512) void k_attn(
    const short* __restrict__ emb_bf,   // [4096][128] bf16
    const short* __restrict__ Wp,       // [3][8][128 i][128 k]
    short* __restrict__ ctx2)           // [4096 out-rows][h*128+i] bf16
{
    __shared__ short lds[6144];         // 12 KB
    __shared__ float redS[8], redQ[8];
    const int bid = blockIdx.x;         // 0..2047
    const int pp2 = bid >> 3, h = bid & 7;   // patch-pair, head
    const int t = threadIdx.x;          // 0..511
    const int w = t >> 6, lane = t & 63;
    const int m16 = lane & 15, quad = lane >> 4, q8 = quad * 8;
    const int l31 = lane & 31, hi = lane >> 5;
    const int ml = w >> 2;              // wave's map (local patch) 0/1
    const int wm = w & 3;               // wave-in-map 0..3 (= its band)

    // ===== QKV: (16x128) @ W_h (128x128) x3, 16x16x32; 3 tiles/wave =====
    {
        bfrag a[4];
        #pragma unroll
        for (int ks = 0; ks < 4; ++ks)
            a[ks] = *(const bfrag*)&emb_bf[(size_t)(pp2*16 + m16)*128 + ks*32 + q8];
        #pragma unroll
        for (int tt = 0; tt < 3; ++tt) {
            const int nt = w * 3 + tt;            // 0..23 = {q,k,v} x 8 i-tiles
            const int x  = nt >> 3;
            const int i0 = (nt & 7) * 16;
            const short* Wb = Wp + ((x*8 + h)*128 + i0 + m16) * 128;
            bfrag bb[4];
            #pragma unroll
            for (int ks = 0; ks < 4; ++ks)
                bb[ks] = *(const bfrag*)&Wb[ks*32 + q8];
            f32x4 c0 = {0.f,0.f,0.f,0.f};
            #pragma unroll
            for (int ks = 0; ks < 4; ++ks)
                c0 = __builtin_amdgcn_mfma_f32_16x16x32_bf16(a[ks], bb[ks], c0, 0,0,0);
            const int plt = quad >> 1;            // patch of these C rows
            const int p0  = (quad & 1) * 4;       // token base 0/4
            const int col = i0 + m16;
            if (x < 2) {                          // Qt/Kt transposed [i][p], b64
                int2 v;
                v.x = f2bf_pk(c0[1], c0[0]);
                v.y = f2bf_pk(c0[3], c0[2]);
                *(int2*)&lds[(x ? KT : QT) + plt*1024 + col*8 + p0] = v;
            } else {                              // V natural, chunk-swizzled
                #pragma unroll
                for (int r = 0; r < 4; ++r) {
                    const int p = p0 + r;
                    const int phys = ((col >> 3) + p + 2*plt) & 15;
                    lds[VS + plt*1024 + p*128 + phys*8 + (col & 7)] = f2bf(c0[r]);
                }
            }
        }
    }
    __syncthreads();

    // ===== hoist fragments (map ml) =====
    // V A-frags, permuted j-enumeration matching S^T C-layout (R9-verified):
    //   slot (kt=2mt+g, k=8hi+jj) <-> j = 32mt + 16g + 4hi + (jj&3) + 8(jj>>2)
    bfrag av[8];
    #pragma unroll
    for (int mt = 0; mt < 4; ++mt)
        #pragma unroll
        for (int g = 0; g < 2; ++g) {
            const int kt = 2*mt + g;
            if (l31 < 8) {
                const int base = VS + ml*1024 + l31*128;
                const int c0i = 4*mt + 2*g;
                const short4 lo = *(const short4*)
                    &lds[base + (((c0i + 0) + l31 + 2*ml) & 15)*8 + 4*hi];
                const short4 hi4 = *(const short4*)
                    &lds[base + (((c0i + 1) + l31 + 2*ml) & 15)*8 + 4*hi];
                bfrag f;
                f[0]=lo.x; f[1]=lo.y; f[2]=lo.z; f[3]=lo.w;
                f[4]=hi4.x; f[5]=hi4.y; f[6]=hi4.z; f[7]=hi4.w;
                av[kt] = f;
            } else if (l31 == 8) {      // ones row -> O row p=8 = rowsum_i
                bfrag o;
                #pragma unroll
                for (int j = 0; j < 8; ++j) o[j] = (short)0x3F80;
                av[kt] = o;
            } else
                av[kt] = bzero();
        }
    bfrag ak[4], bq;                    // scores: A[m=j][k=p], B[k=p][n=i]
    #pragma unroll
    for (int mt = 0; mt < 4; ++mt)
        ak[mt] = (hi == 0) ? *(const bfrag*)&lds[KT + ml*1024 + (32*mt + l31)*8] : bzero();
    bq = (hi == 0) ? *(const bfrag*)&lds[QT + ml*1024 + (32*wm + l31)*8] : bzero();

    // ===== stats: this wave's 4 tiles (its i-band), combine 4 waves/map =====
    float rs2, nbias;
    {
        float ls = 0.f, lq = 0.f;
        #pragma unroll
        for (int mt = 0; mt < 4; ++mt) {
            f32x16 c = {};
            c = __builtin_amdgcn_mfma_f32_32x32x16_bf16(ak[mt], bq, c, 0,0,0);
            #pragma unroll
            for (int r = 0; r < 16; ++r) { ls += c[r]; lq = fmaf(c[r], c[r], lq); }
        }
        #pragma unroll
        for (int off = 1; off <= 32; off <<= 1) {
            ls += __shfl_xor(ls, off);
            lq += __shfl_xor(lq, off);
        }
        if (lane == 0) { redS[w] = ls; redQ[w] = lq; }
        __syncthreads();
        const float st = redS[ml*4+0] + redS[ml*4+1] + redS[ml*4+2] + redS[ml*4+3];
        const float qt = redQ[ml*4+0] + redQ[ml*4+1] + redQ[ml*4+2] + redQ[ml*4+3];
        const float mean = st * (1.f / 16384.f);
        const float var  = qt * (1.f / 16384.f) - mean * mean;
        rs2   = rsqrtf(var + 1e-5f) * 1.44269504f;       // fold log2(e)
        nbias = -mean * rs2;
    }

    // out-row mapping (p = 4*hi + r for r = 0..3)
    int orow[4];
    {
        const int pat = pp2*2 + ml;
        const int bb = pat >> 5, rem = pat & 31;
        const int dd = rem >> 4, hh2 = (rem >> 2) & 3, ww2 = rem & 3;
        #pragma unroll
        for (int r = 0; r < 4; ++r) {
            const int p = 4*hi + r;
            const int p1 = p >> 2, p2 = (p >> 1) & 1, p3 = p & 1;
            orow[r] = bb*256 + ((((dd*2 + p1)*4 + hh2)*2 + p2)*4 + ww2)*2 + p3;
        }
    }

    // ===== pass 2: ONE band (wm): S^T -> exp (in-lane) -> PV -> store =====
    {
        f32x16 O = {};
        #pragma unroll
        for (int mt = 0; mt < 4; ++mt) {
            f32x16 c = {};
            c = __builtin_amdgcn_mfma_f32_32x32x16_bf16(ak[mt], bq, c, 0,0,0);
            #pragma unroll
            for (int g = 0; g < 2; ++g) {
                float e[8];
                #pragma unroll
                for (int jj = 0; jj < 8; ++jj)
                    e[jj] = fast_exp2(fmaf(c[8*g + jj], rs2, nbias));
                i32x4 vi;
                vi[0] = f2bf_pk(e[1], e[0]);
                vi[1] = f2bf_pk(e[3], e[2]);
                vi[2] = f2bf_pk(e[5], e[4]);
                vi[3] = f2bf_pk(e[7], e[6]);
                const bfrag bp = __builtin_bit_cast(bfrag, vi);
                O = __builtin_amdgcn_mfma_f32_32x32x16_bf16(av[2*mt + g], bp, O, 0,0,0);
            }
        }
        // row sums live in O row p=8 = reg 4 on hi=0 lanes
        const float o4x  = __shfl_xor(O[4], 32);
        const float srow = hi ? o4x : O[4];
        const float iv   = __builtin_amdgcn_rcpf(srow);
        const int colg   = h*128 + 32*wm + l31;
        #pragma unroll
        for (int r = 0; r < 4; ++r)
            ctx2[(size_t)orow[r] * 1024 + colg] = f2bf(O[r] * iv);
    }
}

// ---------------- k_out (R7-verified): 256 blocks, 16 rows each --------------
__global__ __launch_bounds__(256) void k_out(
    const short* __restrict__ ctx2,    // [4096][1024]
    const short* __restrict__ Wout_t,  // [128 col][1024 k]
    float* __restrict__ out)           // [4096][128]
{
    const int t = threadIdx.x;
    const int w = t >> 6, lane = t & 63;
    const int m16 = lane & 15, quad = lane >> 4, q8 = quad * 8;
    const int row0 = blockIdx.x * 16;

    f32x4 acc0 = {0.f,0.f,0.f,0.f}, acc1 = {0.f,0.f,0.f,0.f};
    const short* ar = ctx2   + (size_t)(row0 + m16) * 1024 + q8;
    const short* b0 = Wout_t + (size_t)((w*2 + 0)*16 + m16) * 1024 + q8;
    const short* b1 = Wout_t + (size_t)((w*2 + 1)*16 + m16) * 1024 + q8;
    #pragma unroll 4
    for (int ks = 0; ks < 32; ++ks) {
        const bfrag a   = *(const bfrag*)&ar[ks*32];
        const bfrag vb0 = *(const bfrag*)&b0[ks*32];
        const bfrag vb1 = *(const bfrag*)&b1[ks*32];
        acc0 = __builtin_amdgcn_mfma_f32_16x16x32_bf16(a, vb0, acc0, 0, 0, 0);
        acc1 = __builtin_amdgcn_mfma_f32_16x16x32_bf16(a, vb1, acc1, 0, 0, 0);
    }
    const int r0 = quad * 4;
    #pragma unroll
    for (int r = 0; r < 4; ++r) {
        out[(size_t)(row0 + r0 + r)*128 + (w*2 + 0)*16 + m16] = acc0[r];
        out[(size_t)(row0 + r0 + r)*128 + (w*2 + 1)*16 + m16] = acc1[r];
    }
}

extern "C" void kernel_launch(void* const* d_in, const int* in_sizes, int n_in,
                              void* d_out, int out_size, void* d_ws, size_t ws_size,
                              hipStream_t stream) {
    const float* emb  = (const float*)d_in[0];   // (512, 8, 128)
    const float* Wq   = (const float*)d_in[1];   // (128, 1024)
    const float* Wk   = (const float*)d_in[2];
    const float* Wv   = (const float*)d_in[3];
    const float* Wout = (const float*)d_in[4];   // (1024, 128)
    float* out = (float*)d_out;                  // 524288 floats

    short* ctx2   = (short*)d_ws;                // 4194304 shorts (8 MB)
    short* Wp     = ctx2 + 4194304;              // 393216
    short* Wout_t = Wp + 393216;                 // 131072
    short* emb_bf = Wout_t + 131072;             // 524288   (total ~10.1 MB)

    k_conv<<<160, 256, 0, stream>>>(Wq, Wk, Wv, Wout, emb, Wp, Wout_t, emb_bf);
    k_attn<<<2048, 512, 0, stream>>>(emb_bf, Wp, ctx2);
    k_out<<<256, 256, 0, stream>>>(ctx2, Wout_t, out);
}